// Round 3
// baseline (327.171 us; speedup 1.0000x reference)
//
#include <hip/hip_runtime.h>

// KappaGCN layer on MI355X. KAPPA=-1, N=8192, D=512.
// Round 3: fuse A fp32->bf16 conversion AND denom/alpha row-reductions into
// the big split-K GEMM (reg-staged A with v_cvt_pk_bf16_f32); same kernel
// with dosum=0 reads X fp32 directly (conv_bf16 and convA_rowred deleted).

#define NR 8192
#define DD 512

typedef unsigned int u32;
typedef unsigned short u16;
typedef __attribute__((ext_vector_type(8))) short bf16x8;
typedef __attribute__((ext_vector_type(4))) float f32x4;

__device__ __forceinline__ u16 f2bf(float f) {
  u32 u = __float_as_uint(f);
  u32 r = u + 0x7FFFu + ((u >> 16) & 1u);   // round-to-nearest-even
  return (u16)(r >> 16);
}

__device__ __forceinline__ u32 cvtpk(float lo, float hi) {
  u32 r;
  asm("v_cvt_pk_bf16_f32 %0, %1, %2" : "=v"(r) : "v"(lo), "v"(hi));
  return r;
}

__device__ __forceinline__ void gload16(const void* g, void* l) {
  __builtin_amdgcn_global_load_lds(
      (const __attribute__((address_space(1))) u32*)g,
      (__attribute__((address_space(3))) u32*)l, 16, 0, 0);
}

__device__ __forceinline__ float wred(float v) {
  #pragma unroll
  for (int off = 32; off; off >>= 1) v += __shfl_xor(v, off, 64);
  return v;
}

// W [K=512][N=512] fp32 -> Wt [N][K] bf16
__global__ __launch_bounds__(256) void conv_wt(const float* __restrict__ W,
                                               u16* __restrict__ Wt) {
  const int idx = blockIdx.x * 256 + threadIdx.x;  // 0..32767
  const int n  = idx >> 6;
  const int k0 = (idx & 63) * 8;
  u32 r[4];
  #pragma unroll
  for (int j = 0; j < 4; ++j) {
    float lo = W[(size_t)(k0 + 2*j    ) * DD + n];
    float hi = W[(size_t)(k0 + 2*j + 1) * DD + n];
    r[j] = (u32)f2bf(lo) | ((u32)f2bf(hi) << 16);
  }
  *(uint4*)(Wt + (size_t)n * DD + k0) = *(const uint4*)r;
}

// ---------------- GEMM: C[M][N] = Af[M][K](fp32->bf16) * Bt[N][K](bf16) ----
// 128x128 tile, BK=32, 4 waves (2x2). A is reg-staged fp32 -> cvt_pk -> LDS.
// Split-K + sibling-XCD mapping (nt-siblings share A panel on one XCD L2).
// dosum: nt==0 blocks write per-(kc,row) fp32 partials of sum(A) and
// sum(A*(gamma-1)) -- deterministic, no atomics.
__global__ __launch_bounds__(256) void gemm_af32_sk(
    const float* __restrict__ Af, const u16* __restrict__ Bt,
    const float* __restrict__ g1v,
    float* __restrict__ C0, float* __restrict__ Cext,
    float* __restrict__ denp, float* __restrict__ alp,
    int M, int N, int K, int kchunk, int ntm, int dosum) {
  constexpr int BK = 32;
  __shared__ __align__(16) u16 ldsA[2][128 * BK];
  __shared__ __align__(16) u16 ldsB[2][128 * BK];
  const int p  = blockIdx.x;
  const int q  = (p >> 5) * 8 + (p & 7);
  const int nt = (p >> 3) & 3;
  const int mt = q % ntm;
  const int kc = q / ntm;

  const int t = threadIdx.x;
  const int lane = t & 63, w = t >> 6;
  const int wm = w >> 1, wn = w & 1;
  const int m0 = mt * 128, n0 = nt * 128;
  const int kbeg = kc * kchunk;
  const int lr = lane & 15, lk = lane >> 4;

  // B staging via global_load_lds (bf16, linear)
  const int rowB = t >> 2, c8 = (t & 3) * 8;
  const u16* gB = Bt + (size_t)(n0 + rowB) * K + kbeg + c8;
  const size_t rstepB = (size_t)64 * K;

  // A reg-staging: thread covers row rA, 16 consecutive k at ka
  const int rA = t >> 1;
  const int ka = (t & 1) * 16;
  const float* gA = Af + (size_t)(m0 + rA) * K + kbeg + ka;
  const float* gG = g1v + kbeg + ka;
  const bool doRS = dosum && (nt == 0);
  float sA = 0.f, sD = 0.f;

  f32x4 acc[4][4];
  #pragma unroll
  for (int i = 0; i < 4; ++i)
    #pragma unroll
    for (int j = 0; j < 4; ++j) acc[i][j] = (f32x4){0.f, 0.f, 0.f, 0.f};

  const int nT = kchunk / BK;

  // ---- prologue: stage tile 0 into buf 0 ----
  {
    float4 x0 = *(const float4*)(gA + 0);
    float4 x1 = *(const float4*)(gA + 4);
    float4 x2 = *(const float4*)(gA + 8);
    float4 x3 = *(const float4*)(gA + 12);
    gload16(gB,          &ldsB[0][w * 512]);
    gload16(gB + rstepB, &ldsB[0][2048 + w * 512]);
    if (doRS) {
      float4 q0 = *(const float4*)(gG + 0);
      float4 q1 = *(const float4*)(gG + 4);
      float4 q2 = *(const float4*)(gG + 8);
      float4 q3 = *(const float4*)(gG + 12);
      sA += ((x0.x+x0.y)+(x0.z+x0.w)) + ((x1.x+x1.y)+(x1.z+x1.w))
          + ((x2.x+x2.y)+(x2.z+x2.w)) + ((x3.x+x3.y)+(x3.z+x3.w));
      sD += (x0.x*q0.x + x0.y*q0.y + x0.z*q0.z + x0.w*q0.w)
          + (x1.x*q1.x + x1.y*q1.y + x1.z*q1.z + x1.w*q1.w)
          + (x2.x*q2.x + x2.y*q2.y + x2.z*q2.z + x2.w*q2.w)
          + (x3.x*q3.x + x3.y*q3.y + x3.z*q3.z + x3.w*q3.w);
    }
    u32* d = (u32*)&ldsA[0][rA * BK + ka];
    *(uint4*)d       = (uint4){cvtpk(x0.x,x0.y), cvtpk(x0.z,x0.w),
                               cvtpk(x1.x,x1.y), cvtpk(x1.z,x1.w)};
    *((uint4*)d + 1) = (uint4){cvtpk(x2.x,x2.y), cvtpk(x2.z,x2.w),
                               cvtpk(x3.x,x3.y), cvtpk(x3.z,x3.w)};
  }
  __syncthreads();

  for (int tt = 0; tt < nT; ++tt) {
    const int cur = tt & 1, nxt = cur ^ 1;
    const bool hn = (tt + 1 < nT);
    float4 x0, x1, x2, x3;
    if (hn) {
      const float* pa = gA + (tt + 1) * BK;
      x0 = *(const float4*)(pa + 0);
      x1 = *(const float4*)(pa + 4);
      x2 = *(const float4*)(pa + 8);
      x3 = *(const float4*)(pa + 12);
      gload16(gB + (tt + 1) * BK,          &ldsB[nxt][w * 512]);
      gload16(gB + (tt + 1) * BK + rstepB, &ldsB[nxt][2048 + w * 512]);
    }
    bf16x8 af[4], bv[4];
    #pragma unroll
    for (int i = 0; i < 4; ++i) {
      af[i] = *(const bf16x8*)&ldsA[cur][(wm * 64 + i * 16 + lr) * BK + lk * 8];
      bv[i] = *(const bf16x8*)&ldsB[cur][(wn * 64 + i * 16 + lr) * BK + lk * 8];
    }
    #pragma unroll
    for (int mi = 0; mi < 4; ++mi)
      #pragma unroll
      for (int ni = 0; ni < 4; ++ni)
        acc[mi][ni] = __builtin_amdgcn_mfma_f32_16x16x32_bf16(
            af[mi], bv[ni], acc[mi][ni], 0, 0, 0);
    if (hn) {
      if (doRS) {
        const float* pg = gG + (tt + 1) * BK;
        float4 q0 = *(const float4*)(pg + 0);
        float4 q1 = *(const float4*)(pg + 4);
        float4 q2 = *(const float4*)(pg + 8);
        float4 q3 = *(const float4*)(pg + 12);
        sA += ((x0.x+x0.y)+(x0.z+x0.w)) + ((x1.x+x1.y)+(x1.z+x1.w))
            + ((x2.x+x2.y)+(x2.z+x2.w)) + ((x3.x+x3.y)+(x3.z+x3.w));
        sD += (x0.x*q0.x + x0.y*q0.y + x0.z*q0.z + x0.w*q0.w)
            + (x1.x*q1.x + x1.y*q1.y + x1.z*q1.z + x1.w*q1.w)
            + (x2.x*q2.x + x2.y*q2.y + x2.z*q2.z + x2.w*q2.w)
            + (x3.x*q3.x + x3.y*q3.y + x3.z*q3.z + x3.w*q3.w);
      }
      u32* d = (u32*)&ldsA[nxt][rA * BK + ka];
      *(uint4*)d       = (uint4){cvtpk(x0.x,x0.y), cvtpk(x0.z,x0.w),
                                 cvtpk(x1.x,x1.y), cvtpk(x1.z,x1.w)};
      *((uint4*)d + 1) = (uint4){cvtpk(x2.x,x2.y), cvtpk(x2.z,x2.w),
                                 cvtpk(x3.x,x3.y), cvtpk(x3.z,x3.w)};
    }
    __syncthreads();
  }

  if (doRS) {
    sA += __shfl_xor(sA, 1, 64);
    sD += __shfl_xor(sD, 1, 64);
    if ((t & 1) == 0) {
      alp [(size_t)kc * M + m0 + rA] = sA;
      denp[(size_t)kc * M + m0 + rA] = sD;
    }
  }

  float* C = (kc == 0) ? C0 : (Cext + (size_t)(kc - 1) * M * N);
  // C/D layout: col = lane&15, row = (lane>>4)*4 + reg   [m89-verified]
  float* Cw = C + (size_t)(m0 + wm * 64 + lk * 4) * N + n0 + wn * 64 + lr;
  #pragma unroll
  for (int mi = 0; mi < 4; ++mi)
    #pragma unroll
    for (int ni = 0; ni < 4; ++ni)
      #pragma unroll
      for (int v = 0; v < 4; ++v)
        Cw[(size_t)(mi * 16 + v) * N + ni * 16] = acc[mi][ni][v];
}

// ---------------- row stats (mobius_matvec scalars + gamma) ----------------
__global__ __launch_bounds__(256) void rowstats(const float* __restrict__ X,
                                                const float* __restrict__ mx,
                                                float* __restrict__ fg,
                                                float* __restrict__ g1) {
  const int row  = (blockIdx.x << 2) + (threadIdx.x >> 6);
  const int lane = threadIdx.x & 63;
  const float* xr = X  + (size_t)row * DD + lane * 8;
  const float* mr = mx + (size_t)row * DD + lane * 8;
  float4 a0 = *(const float4*)xr, a1 = *(const float4*)(xr + 4);
  float4 b0 = *(const float4*)mr, b1 = *(const float4*)(mr + 4);
  float sx = a0.x*a0.x + a0.y*a0.y + a0.z*a0.z + a0.w*a0.w
           + a1.x*a1.x + a1.y*a1.y + a1.z*a1.z + a1.w*a1.w;
  float sm = b0.x*b0.x + b0.y*b0.y + b0.z*b0.z + b0.w*b0.w
           + b1.x*b1.x + b1.y*b1.y + b1.z*b1.z + b1.w*b1.w;
  sx = wred(sx); sm = wred(sm);
  if (lane == 0) {
    float xn  = sqrtf(fmaxf(sx, 1e-20f));
    float mxn = sqrtf(fmaxf(sm, 1e-20f));
    float at  = atanhf(fminf(xn, 0.9999999f));
    float t_  = tanhf(mxn / xn * at);
    bool  z   = (mxn <= 1e-10f);
    float factor = z ? 0.f : t_ / mxn;
    float xwsq   = z ? 0.f : t_ * t_ * (sm / (mxn * mxn));
    float g = 2.f / (1.f - xwsq);          // kappa = -1
    g = fmaxf(g, 1e-15f);
    fg[row] = factor * g;
    g1[row] = g - 1.f;
  }
}

// ---------------- B_T build: Bt[d][j] = fg[j] * mx[j][d] (bf16) -----------
__global__ __launch_bounds__(256) void build_bt(const float* __restrict__ mx,
                                                const float* __restrict__ fg,
                                                u16* __restrict__ Bt) {
  __shared__ float tile[64][65];
  const int j0 = blockIdx.x * 64, d0 = blockIdx.y * 64;
  const int t = threadIdx.x;
  const int r0 = t >> 4, c4 = (t & 15) * 4;
  #pragma unroll
  for (int p = 0; p < 4; ++p) {
    const int r = r0 + p * 16;
    const float s = fg[j0 + r];
    float4 v = *(const float4*)&mx[(size_t)(j0 + r) * DD + d0 + c4];
    tile[r][c4 + 0] = s * v.x; tile[r][c4 + 1] = s * v.y;
    tile[r][c4 + 2] = s * v.z; tile[r][c4 + 3] = s * v.w;
  }
  __syncthreads();
  const int dr = t >> 2, jc = (t & 3) * 16;
  u32 r[8];
  #pragma unroll
  for (int u = 0; u < 8; ++u) {
    float lo = tile[jc + 2 * u][dr];
    float hi = tile[jc + 2 * u + 1][dr];
    r[u] = (u32)f2bf(lo) | ((u32)f2bf(hi) << 16);
  }
  u32* dst = (u32*)(Bt + (size_t)(d0 + dr) * NR + j0 + jc);
  *(uint4*)dst       = *(const uint4*)&r[0];
  *((uint4*)dst + 1) = *(const uint4*)&r[4];
}

// ---------------- epilogue (sums split-K partials + den/al partials) -------
__global__ __launch_bounds__(256) void epilogue(const float* __restrict__ P0,
                                                const float* __restrict__ P1,
                                                const float* __restrict__ P2,
                                                const float* __restrict__ P3,
                                                const float* __restrict__ denp,
                                                const float* __restrict__ alp,
                                                float* __restrict__ out) {
  const int row  = (blockIdx.x << 2) + (threadIdx.x >> 6);
  const int lane = threadIdx.x & 63;
  const size_t ro = (size_t)row * DD + lane * 8;
  float4 n0 = *(const float4*)(P0 + ro), n1 = *(const float4*)(P0 + ro + 4);
  float4 a, b;
  a = *(const float4*)(P1 + ro); b = *(const float4*)(P1 + ro + 4);
  n0.x += a.x; n0.y += a.y; n0.z += a.z; n0.w += a.w;
  n1.x += b.x; n1.y += b.y; n1.z += b.z; n1.w += b.w;
  a = *(const float4*)(P2 + ro); b = *(const float4*)(P2 + ro + 4);
  n0.x += a.x; n0.y += a.y; n0.z += a.z; n0.w += a.w;
  n1.x += b.x; n1.y += b.y; n1.z += b.z; n1.w += b.w;
  a = *(const float4*)(P3 + ro); b = *(const float4*)(P3 + ro + 4);
  n0.x += a.x; n0.y += a.y; n0.z += a.z; n0.w += a.w;
  n1.x += b.x; n1.y += b.y; n1.z += b.z; n1.w += b.w;

  float de = 0.f, alpha = 0.f;
  #pragma unroll
  for (int kc = 0; kc < 4; ++kc) {
    de    += denp[kc * NR + row];
    alpha += alp [kc * NR + row];
  }
  de = (de >= 0.f ? 1.f : -1.f) * fmaxf(fabsf(de), 1e-10f);

  float v[8] = {n0.x / de, n0.y / de, n0.z / de, n0.w / de,
                n1.x / de, n1.y / de, n1.z / de, n1.w / de};
  float sq = 0.f;
  #pragma unroll
  for (int j = 0; j < 8; ++j) sq += v[j] * v[j];
  sq = wred(sq);
  float s1 = 1.f + sqrtf(fmaxf(1.f - sq, 1e-10f));     // 1+sqrt(max(1+k*sq,EPS))
  float an = sqrtf(fmaxf(sq / (s1 * s1), 1e-20f));     // ||a_mean|| clamped
  float t2 = tanhf(alpha * atanhf(fminf(an, 0.9999999f)));
  float f2 = t2 / (an * s1);                           // res = f2 * v
  float xsq = f2 * f2 * sq;
  float xn = sqrtf(fmaxf(xsq, 1e-20f));
  float lf = atanhf(fminf(xn, 0.9999999f)) / xn;       // logmap0 scale
  float u[8]; float us = 0.f;
  #pragma unroll
  for (int j = 0; j < 8; ++j) {
    u[j] = fmaxf(lf * f2 * v[j], 0.f);                 // relu(log0)
    us += u[j] * u[j];
  }
  us = wred(us);
  float un = sqrtf(fmaxf(us, 1e-20f));
  float ef = tanhf(un) / un;                           // expmap0 scale
  float o[8];
  #pragma unroll
  for (int j = 0; j < 8; ++j) o[j] = ef * u[j];
  float* orow = out + (size_t)row * DD + lane * 8;
  *(float4*)orow       = (float4){o[0], o[1], o[2], o[3]};
  *(float4*)(orow + 4) = (float4){o[4], o[5], o[6], o[7]};
}

// ---------------- launch ----------------
extern "C" void kernel_launch(void* const* d_in, const int* in_sizes, int n_in,
                              void* d_out, int out_size, void* d_ws, size_t ws_size,
                              hipStream_t stream) {
  const float* X = (const float*)d_in[0];
  const float* A = (const float*)d_in[1];
  const float* W = (const float*)d_in[2];
  float* out = (float*)d_out;
  char* ws = (char*)d_ws;

  float* mx   = (float*)(ws);                 // 16777216 B (= split-K P0, nom)
  float* Pext = (float*)(ws + 16777216);      // 3 x 16777216 B      -> 67108864
  u16*   Bt   = (u16*)(ws + 67108864);        // 8388608 B           -> 75497472
  u16*   Wt   = (u16*)(ws + 75497472);        // 524288 B            -> 76021760
  float* fg   = (float*)(ws + 76021760);      // 32768 B             -> 76054528
  float* g1   = (float*)(ws + 76054528);      // 32768 B             -> 76087296
  float* denp = (float*)(ws + 76087296);      // 4*32768 B           -> 76218368
  float* alp  = (float*)(ws + 76218368);      // 4*32768 B           -> 76349440

  const size_t MNf = (size_t)NR * DD;         // floats per partial

  conv_wt<<<128, 256, 0, stream>>>(W, Wt);
  // mx = X @ W (fp32 X read directly; no split; dosum=0)
  gemm_af32_sk<<<256, 256, 0, stream>>>(X, Wt, g1, mx, mx, denp, alp,
                                        NR, DD, DD, DD, 64, 0);
  rowstats<<<2048, 256, 0, stream>>>(X, mx, fg, g1);
  build_bt<<<dim3(128, 8), 256, 0, stream>>>(mx, fg, Bt);
  // nom = A @ Bt^T, split-K=4, fused denom/alpha partials; P0 overlays mx
  gemm_af32_sk<<<1024, 256, 0, stream>>>(A, Bt, g1, mx, Pext, denp, alp,
                                         NR, DD, NR, NR / 4, 64, 1);
  epilogue<<<2048, 256, 0, stream>>>(mx, Pext, Pext + MNf, Pext + 2 * MNf,
                                     denp, alp, out);
}

// Round 4
// 217.239 us; speedup vs baseline: 1.5060x; 1.5060x over previous
//
#include <hip/hip_runtime.h>

// KappaGCN layer on MI355X. KAPPA=-1, N=8192, D=512.
// Round 4: A staged fp32 via global_load_lds (fire-and-forget pipeline kept),
// LDS->frag cvt_pk to bf16; 32B-block XOR swizzle on A tile (pre-swizzled
// global source), 16B-slot swizzle on Bt/Wt (written pre-swizzled by
// producers); denom/alpha fused as 4 extra MFMAs vs {g1,1} B-fragment.
// convA_rowred pass deleted (-402 MB HBM).

#define NR 8192
#define DD 512

typedef unsigned int u32;
typedef unsigned short u16;
typedef __attribute__((ext_vector_type(8))) short bf16x8;
typedef __attribute__((ext_vector_type(4))) float f32x4;

__device__ __forceinline__ u16 f2bf(float f) {
  u32 u = __float_as_uint(f);
  u32 r = u + 0x7FFFu + ((u >> 16) & 1u);   // round-to-nearest-even
  return (u16)(r >> 16);
}

__device__ __forceinline__ u32 cvtpk(float lo, float hi) {
  u32 r;
  asm("v_cvt_pk_bf16_f32 %0, %1, %2" : "=v"(r) : "v"(lo), "v"(hi));
  return r;
}

__device__ __forceinline__ void gload16(const void* g, void* l) {
  __builtin_amdgcn_global_load_lds(
      (const __attribute__((address_space(1))) u32*)g,
      (__attribute__((address_space(3))) u32*)l, 16, 0, 0);
}

__device__ __forceinline__ float wred(float v) {
  #pragma unroll
  for (int off = 32; off; off >>= 1) v += __shfl_xor(v, off, 64);
  return v;
}

// W [K=512][N=512] fp32 -> Wt [N][K] bf16, 16B-slot swizzled per 32-k chunk
__global__ __launch_bounds__(256) void conv_wt(const float* __restrict__ W,
                                               u16* __restrict__ Wt) {
  const int idx = blockIdx.x * 256 + threadIdx.x;  // 0..32767
  const int n  = idx >> 6;
  const int k0 = (idx & 63) * 8;
  u32 r[4];
  #pragma unroll
  for (int j = 0; j < 4; ++j) {
    float lo = W[(size_t)(k0 + 2*j    ) * DD + n];
    float hi = W[(size_t)(k0 + 2*j + 1) * DD + n];
    r[j] = (u32)f2bf(lo) | ((u32)f2bf(hi) << 16);
  }
  // slot = (k0>>3)&3 = idx&3 ; chunk = (idx&63)>>2 ; phys = slot ^ (n&3)
  const int dst = n * DD + ((idx & 63) >> 2) * 32 + (((idx & 3) ^ (n & 3)) * 8);
  *(uint4*)(Wt + dst) = *(const uint4*)r;
}

// ---------------- GEMM: C[M][N] = Af[M][K](fp32) * Bt[N][K](bf16,swz) ------
// 128x128 tile, BK=32, 4 waves (2x2). A staged fp32 via global_load_lds with
// 32B-block swizzle (source pre-swizzled); frags cvt_pk'd to bf16.
// DOSUM: nt==0, wn==0 waves run 4 extra MFMAs vs {g1bf,1} to get per-(kc,row)
// fp32 partials of sum(A*(g-1)) and sum(A).
template <int DOSUM>
__global__ __launch_bounds__(256) void gemm_f32a(
    const float* __restrict__ Af, const u16* __restrict__ Bt,
    const u16* __restrict__ g1bf,
    float* __restrict__ C0, float* __restrict__ Cext,
    float* __restrict__ denp, float* __restrict__ alp,
    int M, int N, int K, int kchunk, int ntm) {
  __shared__ __align__(16) float ldsA[2][4096];   // [128][32] f32, 32B-swz
  __shared__ __align__(16) u16   ldsB[2][4096];   // [128][32] bf16, 16B-swz
  __shared__ __align__(16) u16   ldsG[2048];      // g1bf chunk (DOSUM)
  const int p  = blockIdx.x;
  const int q  = (p >> 5) * 8 + (p & 7);
  const int nt = (p >> 3) & 3;
  const int mt = q % ntm;
  const int kc = q / ntm;

  const int t = threadIdx.x;
  const int lane = t & 63, w = t >> 6;
  const int wm = w >> 1, wn = w & 1;
  const int m0 = mt * 128, n0 = nt * 128;
  const int kbeg = kc * kchunk;
  const int lr = lane & 15, lk = lane >> 4, lr3 = lr & 3;
  const bool doRS = DOSUM && (nt == 0);

  // A staging: thread t, page j: covers lds floats e=t*4+j*1024;
  // row R=(t>>3)+j*32, src col pre-swizzled.
  const int Rb   = t >> 3;
  const int scol = ((((t >> 1) & 3) ^ (Rb & 3)) << 3) + (t & 1) * 4;
  const float* gA0 = Af + (size_t)(m0 + Rb) * K + kbeg + scol;
  const size_t apg = (size_t)32 * K;              // +32 rows per page

  // B staging (linear; Bt already swizzled in global)
  const u16* gB = Bt + (size_t)(n0 + (t >> 2)) * K + kbeg + (t & 3) * 8;
  const size_t rstepB = (size_t)64 * K;

  f32x4 acc[4][4];
  #pragma unroll
  for (int i = 0; i < 4; ++i)
    #pragma unroll
    for (int j = 0; j < 4; ++j) acc[i][j] = (f32x4){0.f, 0.f, 0.f, 0.f};
  f32x4 accS[4];
  #pragma unroll
  for (int i = 0; i < 4; ++i) accS[i] = (f32x4){0.f, 0.f, 0.f, 0.f};

  const int nT = kchunk / 32;

  // ---- prologue ----
  if (doRS) gload16(g1bf + kbeg + w * 512, &ldsG[w * 512]);
  #pragma unroll
  for (int j = 0; j < 4; ++j)
    gload16(gA0 + j * apg, &ldsA[0][w * 256 + j * 1024]);
  gload16(gB,          &ldsB[0][w * 512]);
  gload16(gB + rstepB, &ldsB[0][2048 + w * 512]);
  __syncthreads();

  for (int tt = 0; tt < nT; ++tt) {
    const int cur = tt & 1, nxt = cur ^ 1;
    if (tt + 1 < nT) {
      const int ko = (tt + 1) * 32;
      #pragma unroll
      for (int j = 0; j < 4; ++j)
        gload16(gA0 + ko + j * apg, &ldsA[nxt][w * 256 + j * 1024]);
      gload16(gB + ko,          &ldsB[nxt][w * 512]);
      gload16(gB + ko + rstepB, &ldsB[nxt][2048 + w * 512]);
    }
    bf16x8 af[4], bv[4];
    #pragma unroll
    for (int i = 0; i < 4; ++i) {
      const int ra = (wm * 64 + i * 16 + lr) * 32 + ((lk ^ lr3) << 3);
      f32x4 lo = *(const f32x4*)&ldsA[cur][ra];
      f32x4 hi = *(const f32x4*)&ldsA[cur][ra + 4];
      union { u32 u[4]; bf16x8 v; } pk;
      pk.u[0] = cvtpk(lo.x, lo.y); pk.u[1] = cvtpk(lo.z, lo.w);
      pk.u[2] = cvtpk(hi.x, hi.y); pk.u[3] = cvtpk(hi.z, hi.w);
      af[i] = pk.v;
      const int rb = (wn * 64 + i * 16 + lr) * 32 + ((lk ^ lr3) << 3);
      bv[i] = *(const bf16x8*)&ldsB[cur][rb];
    }
    #pragma unroll
    for (int mi = 0; mi < 4; ++mi)
      #pragma unroll
      for (int ni = 0; ni < 4; ++ni)
        acc[mi][ni] = __builtin_amdgcn_mfma_f32_16x16x32_bf16(
            af[mi], bv[ni], acc[mi][ni], 0, 0, 0);
    if (doRS && wn == 0) {
      bf16x8 gv;
      if (lr == 0) {
        gv = *(const bf16x8*)&ldsG[tt * 32 + lk * 8];
      } else {
        const short s = (lr == 1) ? (short)0x3F80 : (short)0;
        gv = (bf16x8){s, s, s, s, s, s, s, s};
      }
      #pragma unroll
      for (int i = 0; i < 4; ++i)
        accS[i] = __builtin_amdgcn_mfma_f32_16x16x32_bf16(
            af[i], gv, accS[i], 0, 0, 0);
    }
    __syncthreads();
  }

  if (doRS && wn == 0 && lr < 2) {
    float* dst = ((lr == 0) ? denp : alp) + (size_t)kc * M + m0 + wm * 64;
    #pragma unroll
    for (int i = 0; i < 4; ++i)
      #pragma unroll
      for (int v = 0; v < 4; ++v)
        dst[i * 16 + lk * 4 + v] = accS[i][v];
  }

  float* C = (kc == 0) ? C0 : (Cext + (size_t)(kc - 1) * M * N);
  // C/D layout: col = lane&15, row = (lane>>4)*4 + reg   [m89-verified]
  float* Cw = C + (size_t)(m0 + wm * 64 + lk * 4) * N + n0 + wn * 64 + lr;
  #pragma unroll
  for (int mi = 0; mi < 4; ++mi)
    #pragma unroll
    for (int ni = 0; ni < 4; ++ni)
      #pragma unroll
      for (int v = 0; v < 4; ++v)
        Cw[(size_t)(mi * 16 + v) * N + ni * 16] = acc[mi][ni][v];
}

// ---------------- row stats (mobius_matvec scalars + gamma) ----------------
__global__ __launch_bounds__(256) void rowstats(const float* __restrict__ X,
                                                const float* __restrict__ mx,
                                                float* __restrict__ fg,
                                                u16* __restrict__ g1bf) {
  const int row  = (blockIdx.x << 2) + (threadIdx.x >> 6);
  const int lane = threadIdx.x & 63;
  const float* xr = X  + (size_t)row * DD + lane * 8;
  const float* mr = mx + (size_t)row * DD + lane * 8;
  float4 a0 = *(const float4*)xr, a1 = *(const float4*)(xr + 4);
  float4 b0 = *(const float4*)mr, b1 = *(const float4*)(mr + 4);
  float sx = a0.x*a0.x + a0.y*a0.y + a0.z*a0.z + a0.w*a0.w
           + a1.x*a1.x + a1.y*a1.y + a1.z*a1.z + a1.w*a1.w;
  float sm = b0.x*b0.x + b0.y*b0.y + b0.z*b0.z + b0.w*b0.w
           + b1.x*b1.x + b1.y*b1.y + b1.z*b1.z + b1.w*b1.w;
  sx = wred(sx); sm = wred(sm);
  if (lane == 0) {
    float xn  = sqrtf(fmaxf(sx, 1e-20f));
    float mxn = sqrtf(fmaxf(sm, 1e-20f));
    float at  = atanhf(fminf(xn, 0.9999999f));
    float t_  = tanhf(mxn / xn * at);
    bool  z   = (mxn <= 1e-10f);
    float factor = z ? 0.f : t_ / mxn;
    float xwsq   = z ? 0.f : t_ * t_ * (sm / (mxn * mxn));
    float g = 2.f / (1.f - xwsq);          // kappa = -1
    g = fmaxf(g, 1e-15f);
    fg[row] = factor * g;
    g1bf[row] = f2bf(g - 1.f);
  }
}

// ---------------- B_T build: Bt[d][j] = fg[j]*mx[j][d], 16B-slot swizzled --
__global__ __launch_bounds__(256) void build_bt(const float* __restrict__ mx,
                                                const float* __restrict__ fg,
                                                u16* __restrict__ Bt) {
  __shared__ float tile[64][65];
  const int j0 = blockIdx.x * 64, d0 = blockIdx.y * 64;
  const int t = threadIdx.x;
  const int r0 = t >> 4, c4 = (t & 15) * 4;
  #pragma unroll
  for (int p = 0; p < 4; ++p) {
    const int r = r0 + p * 16;
    const float s = fg[j0 + r];
    float4 v = *(const float4*)&mx[(size_t)(j0 + r) * DD + d0 + c4];
    tile[r][c4 + 0] = s * v.x; tile[r][c4 + 1] = s * v.y;
    tile[r][c4 + 2] = s * v.z; tile[r][c4 + 3] = s * v.w;
  }
  __syncthreads();
  const int dr = t >> 2, jc = (t & 3) * 16;
  u32 r[8];
  #pragma unroll
  for (int u = 0; u < 8; ++u) {
    float lo = tile[jc + 2 * u][dr];
    float hi = tile[jc + 2 * u + 1][dr];
    r[u] = (u32)f2bf(lo) | ((u32)f2bf(hi) << 16);
  }
  // logical cols jc..jc+15 -> slots {s0, s0+1} of chunk (jc>>5), phys ^= dr&3
  const int s0 = (jc >> 3) & 3;
  const int px = dr & 3;
  u32* rowp = (u32*)(Bt + (size_t)(d0 + dr) * NR + j0 + (jc & 32));
  *(uint4*)(rowp + ((s0 ^ px) * 4))       = *(const uint4*)&r[0];
  *(uint4*)(rowp + (((s0 + 1) ^ px) * 4)) = *(const uint4*)&r[4];
}

// ---------------- epilogue (sums split-K partials + den/al partials) -------
__global__ __launch_bounds__(256) void epilogue(const float* __restrict__ P0,
                                                const float* __restrict__ P1,
                                                const float* __restrict__ P2,
                                                const float* __restrict__ P3,
                                                const float* __restrict__ denp,
                                                const float* __restrict__ alp,
                                                float* __restrict__ out) {
  const int row  = (blockIdx.x << 2) + (threadIdx.x >> 6);
  const int lane = threadIdx.x & 63;
  const size_t ro = (size_t)row * DD + lane * 8;
  float4 n0 = *(const float4*)(P0 + ro), n1 = *(const float4*)(P0 + ro + 4);
  float4 a, b;
  a = *(const float4*)(P1 + ro); b = *(const float4*)(P1 + ro + 4);
  n0.x += a.x; n0.y += a.y; n0.z += a.z; n0.w += a.w;
  n1.x += b.x; n1.y += b.y; n1.z += b.z; n1.w += b.w;
  a = *(const float4*)(P2 + ro); b = *(const float4*)(P2 + ro + 4);
  n0.x += a.x; n0.y += a.y; n0.z += a.z; n0.w += a.w;
  n1.x += b.x; n1.y += b.y; n1.z += b.z; n1.w += b.w;
  a = *(const float4*)(P3 + ro); b = *(const float4*)(P3 + ro + 4);
  n0.x += a.x; n0.y += a.y; n0.z += a.z; n0.w += a.w;
  n1.x += b.x; n1.y += b.y; n1.z += b.z; n1.w += b.w;

  float de = 0.f, alpha = 0.f;
  #pragma unroll
  for (int kc = 0; kc < 4; ++kc) {
    de    += denp[kc * NR + row];
    alpha += alp [kc * NR + row];
  }
  de = (de >= 0.f ? 1.f : -1.f) * fmaxf(fabsf(de), 1e-10f);

  float v[8] = {n0.x / de, n0.y / de, n0.z / de, n0.w / de,
                n1.x / de, n1.y / de, n1.z / de, n1.w / de};
  float sq = 0.f;
  #pragma unroll
  for (int j = 0; j < 8; ++j) sq += v[j] * v[j];
  sq = wred(sq);
  float s1 = 1.f + sqrtf(fmaxf(1.f - sq, 1e-10f));     // 1+sqrt(max(1+k*sq,EPS))
  float an = sqrtf(fmaxf(sq / (s1 * s1), 1e-20f));     // ||a_mean|| clamped
  float t2 = tanhf(alpha * atanhf(fminf(an, 0.9999999f)));
  float f2 = t2 / (an * s1);                           // res = f2 * v
  float xsq = f2 * f2 * sq;
  float xn = sqrtf(fmaxf(xsq, 1e-20f));
  float lf = atanhf(fminf(xn, 0.9999999f)) / xn;       // logmap0 scale
  float u[8]; float us = 0.f;
  #pragma unroll
  for (int j = 0; j < 8; ++j) {
    u[j] = fmaxf(lf * f2 * v[j], 0.f);                 // relu(log0)
    us += u[j] * u[j];
  }
  us = wred(us);
  float un = sqrtf(fmaxf(us, 1e-20f));
  float ef = tanhf(un) / un;                           // expmap0 scale
  float o[8];
  #pragma unroll
  for (int j = 0; j < 8; ++j) o[j] = ef * u[j];
  float* orow = out + (size_t)row * DD + lane * 8;
  *(float4*)orow       = (float4){o[0], o[1], o[2], o[3]};
  *(float4*)(orow + 4) = (float4){o[4], o[5], o[6], o[7]};
}

// ---------------- launch ----------------
extern "C" void kernel_launch(void* const* d_in, const int* in_sizes, int n_in,
                              void* d_out, int out_size, void* d_ws, size_t ws_size,
                              hipStream_t stream) {
  const float* X = (const float*)d_in[0];
  const float* A = (const float*)d_in[1];
  const float* W = (const float*)d_in[2];
  float* out = (float*)d_out;
  char* ws = (char*)d_ws;

  float* mx   = (float*)(ws);                 // 16777216 B (= split-K P0, nom)
  float* Pext = (float*)(ws + 16777216);      // 3 x 16777216 B      -> 67108864
  u16*   Bt   = (u16*)(ws + 67108864);        // 8388608 B           -> 75497472
  u16*   Wt   = (u16*)(ws + 75497472);        // 524288 B            -> 76021760
  float* fg   = (float*)(ws + 76021760);      // 32768 B             -> 76054528
  u16*   g1bf = (u16*)(ws + 76054528);        // 16384 B             -> 76070912
  float* denp = (float*)(ws + 76087296);      // 4*32768 B           -> 76218368
  float* alp  = (float*)(ws + 76218368);      // 4*32768 B           -> 76349440

  const size_t MNf = (size_t)NR * DD;         // floats per partial

  conv_wt<<<128, 256, 0, stream>>>(W, Wt);
  // mx = X @ W (fp32 X staged directly; no split)
  gemm_f32a<0><<<256, 256, 0, stream>>>(X, Wt, g1bf, mx, mx, denp, alp,
                                        NR, DD, DD, DD, 64);
  rowstats<<<2048, 256, 0, stream>>>(X, mx, fg, g1bf);
  build_bt<<<dim3(128, 8), 256, 0, stream>>>(mx, fg, Bt);
  // nom = A @ Bt^T, split-K=4, fused denom/alpha via extra MFMAs
  gemm_f32a<1><<<1024, 256, 0, stream>>>(A, Bt, g1bf, mx, Pext, denp, alp,
                                         NR, DD, NR, NR / 4, 64);
  epilogue<<<2048, 256, 0, stream>>>(mx, Pext, Pext + MNf, Pext + 2 * MNf,
                                     denp, alp, out);
}